// Round 14
// baseline (848991.504 us; speedup 1.0000x reference)
//
#include <hip/hip_runtime.h>
#include <hip/hip_fp16.h>

// Problem constants
#define Bn  256
#define Tn  512
#define En  256
#define Hn  512
#define G4n 2048   // 4*H
#define KKn 768    // E + H
#define FHn 512

#define GB  32     // batch rows per XCD group
#define NB  32     // blocks per XCD group
#define NH  16     // h-cols per block (x4 gates = 64 gate cols)
#define LDK 768    // LDS row length (f16); swizzle replaces padding
#define CSTRIDE 64 // ints between per-XCD counters (256B)

// XOR swizzle: permute 16B chunks within each 128B window by row&7
#define A_IDX(r, c) ((r) * LDK + (((c) ^ (((r) & 7) << 3))))

typedef _Float16 f16;
typedef _Float16 f16x8 __attribute__((ext_vector_type(8)));
typedef float    f32x4 __attribute__((ext_vector_type(4)));

__device__ __forceinline__ float frcp(float x) { return __builtin_amdgcn_rcpf(x); }
__device__ __forceinline__ float fsig(float x) { return frcp(1.f + __expf(-x)); }
__device__ __forceinline__ float ftanh(float x) {
  x = fminf(fmaxf(x, -15.f), 15.f);
  float e = __expf(2.f * x);
  return 1.f - 2.f * frcp(e + 1.f);
}

// ---- XCD-local primitives (L2 scope; no sc1 => never touches the MALL) ----
__device__ __forceinline__ int read_xcc_id() {
  int x;
  asm volatile("s_getreg_b32 %0, hwreg(HW_REG_XCC_ID)" : "=s"(x));
  return x & 7;
}
__device__ __forceinline__ void store_x4_sc0(f16* p, f16x8 v) {
  asm volatile("global_store_dwordx4 %0, %1, off sc0" :: "v"(p), "v"(v) : "memory");
}
__device__ __forceinline__ f16x8 load_x4_sc0(const f16* p) {   // no waitcnt!
  f16x8 r;
  asm volatile("global_load_dwordx4 %0, %1, off sc0" : "=v"(r) : "v"(p) : "memory");
  return r;
}
__device__ __forceinline__ void waitcnt_vm0() {
  asm volatile("s_waitcnt vmcnt(0)" ::: "memory");
}
__device__ __forceinline__ void atomic_inc_l2(int* p) {
  int one = 1;
  asm volatile("global_atomic_add %0, %1, off" :: "v"(p), "v"(one) : "memory");
}
__device__ __forceinline__ int load_i32_sc0(const int* p) {
  int r;
  asm volatile("global_load_dword %0, %1, off sc0\n\ts_waitcnt vmcnt(0)"
               : "=v"(r) : "v"(p) : "memory");
  return r;
}

// ---------------------------------------------------------------------------
// prep: lengths[b], zero slot/barrier counters, zero h-buffer[0]
// ---------------------------------------------------------------------------
__global__ void prep_kernel(const int* __restrict__ seq, int* __restrict__ lengths,
                            int* __restrict__ slotc, int* __restrict__ cnt,
                            f16* __restrict__ hbuf) {
  const int b = blockIdx.x, tid = threadIdx.x;
  __shared__ int red[256];
  int c = 0;
  for (int t = tid; t < Tn; t += 256) c += (seq[b * Tn + t] != 0) ? 1 : 0;
  red[tid] = c;
  __syncthreads();
  for (int s = 128; s > 0; s >>= 1) { if (tid < s) red[tid] += red[tid + s]; __syncthreads(); }
  if (tid == 0) lengths[b] = red[0];
  if (b == 0 && tid < 8) { slotc[tid * CSTRIDE] = 0; cnt[tid * CSTRIDE] = 0; }
  f16* row = hbuf + (size_t)b * Hn;   // hbuf[0][b][:]
  for (int k = tid; k < Hn; k += 256) row[k] = (f16)0.f;
}

// ---------------------------------------------------------------------------
// Persistent cooperative LSTM. 256 blocks x 145KB LDS => 1 block/CU => exactly
// 32 blocks per XCD. group = physical XCD (HW_REG_XCC_ID), slot = XCD-local
// ticket. Block: batches xcd*32..+32, h-cols slot*16..+16.
// R14 = R12 with two surgical changes (wave-0-ONLY polling preserved --
// multi-wave polling collapsed the kernel twice, R7 & R13):
//  * (B) removed: wave 0's h-store + vmcnt0 + lane0-inc are program-ordered.
//  * waves 1-3 stage x(t+1) concurrently with wave 0's publish+poll.
// Step: MFMA -> act -> (A) -> {wv0: store,vm0,inc,poll | wv1-3: x-stage}
//       -> (C) relay -> h-load -> (D).
// ---------------------------------------------------------------------------
__global__ __launch_bounds__(256, 1)
void lstm_kernel(const int* __restrict__ seq, const float* __restrict__ emb,
                 const float* __restrict__ Wi, const float* __restrict__ Wh,
                 const float* __restrict__ bl,
                 const int* __restrict__ lengths, int* __restrict__ slotc,
                 int* __restrict__ cnt, f16* __restrict__ hbuf)
{
  __shared__ f16 act[GB * LDK];                // [x_t ; h_t] for 32 batches, swizzled
  __shared__ f16 wt[64 * LDK];                 // staging only (dead after init)
  __shared__ __align__(16) f16 hstage[GB][NH];
  __shared__ int s_ids[2];

  const int tid  = threadIdx.x;
  const int lane = tid & 63;
  const int wv   = tid >> 6;

  if (tid == 0) {
    int x = read_xcc_id();
    s_ids[0] = x;
    s_ids[1] = __hip_atomic_fetch_add(&slotc[x * CSTRIDE], 1,
                                      __ATOMIC_RELAXED, __HIP_MEMORY_SCOPE_AGENT) & 31;
  }
  __syncthreads();
  const int xcd   = s_ids[0];
  const int slot  = s_ids[1];
  const int bbase = xcd * GB;
  int* const bar  = cnt + xcd * CSTRIDE;

  // ---- stage weights into LDS (once): wt[c][k], c = w*16 + gate*4 + hloc ----
  {
    const int c = tid & 63, k0 = tid >> 6;
    const int gate = (c >> 2) & 3, w = c >> 4, hl = c & 3;
    const int gc = gate * Hn + slot * NH + w * 4 + hl;
    for (int k = k0; k < KKn; k += 4) {
      float wval = (k < En) ? Wi[(size_t)k * G4n + gc] : Wh[(size_t)(k - En) * G4n + gc];
      wt[A_IDX(c, k)] = (f16)wval;
    }
  }

  const int ca   = lane & 15;          // col within wave's n-tile
  const int gate = ca >> 2, hloc = ca & 3;
  const float bias = bl[gate * Hn + slot * NH + wv * 4 + hloc];
  const int r0 = (lane >> 4) * 4;      // C/D row base (j=0)
  const bool owner = (ca & 12) == 0;   // gate-0 lanes own (row, hcol) state
  const bool isg = (gate == 2);
  const int koff = (lane >> 4) * 8;

  int   lens[2][4];
  float hreg[2][4] = {{0,0,0,0},{0,0,0,0}};
  float creg[2][4] = {{0,0,0,0},{0,0,0,0}};
#pragma unroll
  for (int mt = 0; mt < 2; ++mt)
#pragma unroll
    for (int j = 0; j < 4; ++j)
      lens[mt][j] = lengths[bbase + mt * 16 + r0 + j];

  // ---- initial staging: x(0) and h(0)=0 (plain loads; dispatch-boundary coherent)
#pragma unroll
  for (int pass = 0; pass < 4; ++pass) {
    const int r = wv * 2 + (lane >> 5) + pass * 8;
    int tok = seq[(size_t)(bbase + r) * Tn + 0];
    const float4* er = (const float4*)(emb + (size_t)tok * En + (lane & 31) * 8);
    float4 v0 = er[0], v1 = er[1];
    f16x8 o = { (f16)v0.x,(f16)v0.y,(f16)v0.z,(f16)v0.w,
                (f16)v1.x,(f16)v1.y,(f16)v1.z,(f16)v1.w };
    *(f16x8*)&act[A_IDX(r, (lane & 31) * 8)] = o;
  }
  for (int r = wv; r < GB; r += 4) {
    f16x8 hv = *(const f16x8*)(hbuf + (size_t)(bbase + r) * Hn + lane * 8);
    *(f16x8*)&act[A_IDX(r, En + lane * 8)] = hv;
  }
  __syncthreads();

  // ---- time-invariant B fragments -> registers, pinned via opaque asm ----
  f16x8 bfrag[24];
#pragma unroll
  for (int ki = 0; ki < 24; ++ki) {
    bfrag[ki] = *(const f16x8*)&wt[A_IDX(wv * 16 + ca, ki * 32 + koff)];
    asm volatile("" : "+v"(bfrag[ki]));
  }

  int cur = 0;

  for (int t = 0; t < Tn; ++t) {
    f32x4 acc[2] = {{0,0,0,0},{0,0,0,0}};
#pragma unroll
    for (int ki = 0; ki < 24; ++ki) {
      const int kt = ki * 32;
      f16x8 a0 = *(const f16x8*)&act[A_IDX(ca, kt + koff)];
      f16x8 a1 = *(const f16x8*)&act[A_IDX(16 + ca, kt + koff)];
      acc[0] = __builtin_amdgcn_mfma_f32_16x16x32_f16(a0, bfrag[ki], acc[0], 0, 0, 0);
      acc[1] = __builtin_amdgcn_mfma_f32_16x16x32_f16(a1, bfrag[ki], acc[1], 0, 0, 0);
    }

    // pre-activate on ALL lanes (one exp path: tanh(v) = 2*sig(2v)-1)
    float av[2][4];
#pragma unroll
    for (int mt = 0; mt < 2; ++mt)
#pragma unroll
      for (int j = 0; j < 4; ++j) {
        float v = acc[mt][j] + bias;
        float s = fsig(isg ? 2.f * v : v);
        av[mt][j] = isg ? (2.f * s - 1.f) : s;
      }

    // gather activated f/g/o onto gate-0 lanes; owners update c/h
#pragma unroll
    for (int mt = 0; mt < 2; ++mt) {
      float fv[4], gv[4], ov[4];
#pragma unroll
      for (int j = 0; j < 4; ++j) {
        fv[j] = __shfl_xor(av[mt][j], 4, 64);
        gv[j] = __shfl_xor(av[mt][j], 8, 64);
        ov[j] = __shfl_xor(av[mt][j], 12, 64);
      }
      if (owner) {
#pragma unroll
        for (int j = 0; j < 4; ++j) {
          float cn = fv[j] * creg[mt][j] + av[mt][j] * gv[j];
          float hn = ov[j] * (2.f * fsig(2.f * cn) - 1.f);
          if (t < lens[mt][j]) { creg[mt][j] = cn; hreg[mt][j] = hn; }
          hstage[mt * 16 + r0 + j][wv * 4 + hloc] = (f16)hreg[mt][j];
        }
      }
    }
    __syncthreads();                                  // (A) hstage complete

    const int nxt = cur ^ 1;

    if (t == Tn - 1) {
      if (wv == 0) {                                  // final publish, then exit
        const int row = lane >> 1, half = lane & 1;
        f16x8 v = ((const f16x8*)&hstage[row][0])[half];
        f16* dst = hbuf + ((size_t)nxt * Bn + (bbase + row)) * Hn + slot * NH + half * 8;
        store_x4_sc0(dst, v);
        waitcnt_vm0();
      }
      break;
    }

    if (wv == 0) {
      // wave 0: publish h tile (64x16B), drain, inc, then poll -- all program order
      const int row = lane >> 1, half = lane & 1;
      f16x8 v = ((const f16x8*)&hstage[row][0])[half];
      f16* dst = hbuf + ((size_t)nxt * Bn + (bbase + row)) * Hn + slot * NH + half * 8;
      store_x4_sc0(dst, v);
      waitcnt_vm0();                                  // h tile in L2
      if (lane == 0) atomic_inc_l2(bar);              // publish step t
      const int target = NB * (t + 1);
      int guard = 0;
      while (load_i32_sc0(bar) < target) {            // wave-0-ONLY poll (proven)
        if (++guard > (1 << 14)) break;               // degrade, never wedge
        __builtin_amdgcn_s_sleep(1);
      }
    } else {
      // waves 1-3: stage x(t+1) concurrently (rows 0-11 / 12-21 / 22-31)
      const int base  = (wv == 1) ? 0 : (wv == 2 ? 12 : 22);
      const int nrows = (wv == 1) ? 12 : 10;
      for (int lr = (lane >> 5); lr < nrows; lr += 2) {
        const int r = base + lr;
        int tok = seq[(size_t)(bbase + r) * Tn + (t + 1)];
        const float4* er = (const float4*)(emb + (size_t)tok * En + (lane & 31) * 8);
        float4 v0 = er[0], v1 = er[1];
        f16x8 o = { (f16)v0.x,(f16)v0.y,(f16)v0.z,(f16)v0.w,
                    (f16)v1.x,(f16)v1.y,(f16)v1.z,(f16)v1.w };
        *(f16x8*)&act[A_IDX(r, (lane & 31) * 8)] = o;
      }
    }
    __syncthreads();                                  // (C) relay: barrier passed

    // load h(t+1): 8 rows/wave, 16B/lane, sc0 (L1-bypass, L2-hit)
    {
      const f16* hb = hbuf + (size_t)nxt * Bn * Hn;
      f16x8 hv[8];
#pragma unroll
      for (int i = 0; i < 8; ++i)
        hv[i] = load_x4_sc0(hb + (size_t)(bbase + wv + i * 4) * Hn + lane * 8);
      waitcnt_vm0();
#pragma unroll
      for (int i = 0; i < 8; ++i)
        *(f16x8*)&act[A_IDX(wv + i * 4, En + lane * 8)] = hv[i];
    }
    __syncthreads();                                  // (D) act ready for t+1
    cur = nxt;
  }
}

// ---------------------------------------------------------------------------
// FF head: hidden = tanh(h @ W1 + b1); logits = hidden @ W2 + b2; softmax.
// Final h lives in hbuf[0] (t=511 writes buffer 0).
// ---------------------------------------------------------------------------
__global__ void ff_kernel(const f16* __restrict__ hbuf0, const float* __restrict__ W1,
                          const float* __restrict__ b1, const float* __restrict__ W2,
                          const float* __restrict__ b2, float* __restrict__ out) {
  const int b = blockIdx.x, tid = threadIdx.x;
  __shared__ float hl[Hn];
  __shared__ float hid[FHn];
  __shared__ float red0[256], red1[256];
  for (int k = tid; k < Hn; k += 256) hl[k] = (float)hbuf0[(size_t)b * Hn + k];
  __syncthreads();
  for (int j = tid; j < FHn; j += 256) {
    float s = b1[j];
    for (int k = 0; k < Hn; ++k) s += hl[k] * W1[(size_t)k * FHn + j];
    hid[j] = ftanh(s);
  }
  __syncthreads();
  float p0 = 0.f, p1 = 0.f;
  for (int j = tid; j < FHn; j += 256) {
    p0 += hid[j] * W2[j * 2 + 0];
    p1 += hid[j] * W2[j * 2 + 1];
  }
  red0[tid] = p0; red1[tid] = p1;
  __syncthreads();
  for (int s = 128; s > 0; s >>= 1) {
    if (tid < s) { red0[tid] += red0[tid + s]; red1[tid] += red1[tid + s]; }
    __syncthreads();
  }
  if (tid == 0) {
    float l0 = red0[0] + b2[0], l1 = red1[0] + b2[1];
    float m = fmaxf(l0, l1);
    float e0 = __expf(l0 - m), e1 = __expf(l1 - m);
    float inv = frcp(e0 + e1);
    out[b * 2 + 0] = e0 * inv;
    out[b * 2 + 1] = e1 * inv;
  }
}

// ---------------------------------------------------------------------------
extern "C" void kernel_launch(void* const* d_in, const int* in_sizes, int n_in,
                              void* d_out, int out_size, void* d_ws, size_t ws_size,
                              hipStream_t stream) {
  const int*   seq = (const int*)d_in[0];
  const float* emb = (const float*)d_in[1];
  const float* Wi  = (const float*)d_in[2];
  const float* Wh  = (const float*)d_in[3];
  const float* bl  = (const float*)d_in[4];
  const float* W1  = (const float*)d_in[5];
  const float* b1  = (const float*)d_in[6];
  const float* W2  = (const float*)d_in[7];
  const float* b2  = (const float*)d_in[8];
  (void)in_sizes; (void)n_in; (void)out_size; (void)ws_size;

  char* ws      = (char*)d_ws;
  int*  lengths = (int*)ws;                 // 1 KB
  int*  slotc   = (int*)(ws + 1024);        // 8 counters, 256B apart
  int*  cnt     = (int*)(ws + 4096);        // 8 counters, 256B apart
  f16*  hbuf    = (f16*)(ws + 8192);        // 2 * 256 * 512 * 2B = 512 KB

  prep_kernel<<<dim3(Bn), dim3(256), 0, stream>>>(seq, lengths, slotc, cnt, hbuf);

  void* args[] = { (void*)&seq, (void*)&emb, (void*)&Wi, (void*)&Wh, (void*)&bl,
                   (void*)&lengths, (void*)&slotc, (void*)&cnt, (void*)&hbuf };
  (void)hipLaunchCooperativeKernel((void*)lstm_kernel, dim3(256), dim3(256), args, 0, stream);

  ff_kernel<<<dim3(Bn), dim3(256), 0, stream>>>(hbuf, W1, b1, W2, b2, (float*)d_out);
}

// Round 15
// 2166.077 us; speedup vs baseline: 391.9489x; 391.9489x over previous
//
#include <hip/hip_runtime.h>
#include <hip/hip_fp16.h>

// Problem constants
#define Bn  256
#define Tn  512
#define En  256
#define Hn  512
#define G4n 2048   // 4*H
#define KKn 768    // E + H
#define FHn 512

#define GB  32     // batch rows per XCD group
#define NB  32     // blocks per XCD group
#define NH  16     // h-cols per block (x4 gates = 64 gate cols)
#define LDK 768    // LDS row length (f16); swizzle replaces padding
#define CSTRIDE 64 // ints between per-XCD counters (256B)

// XOR swizzle: permute 16B chunks within each 128B window by row&7
#define A_IDX(r, c) ((r) * LDK + (((c) ^ (((r) & 7) << 3))))

typedef _Float16 f16;
typedef _Float16 f16x8 __attribute__((ext_vector_type(8)));
typedef float    f32x4 __attribute__((ext_vector_type(4)));

__device__ __forceinline__ float frcp(float x) { return __builtin_amdgcn_rcpf(x); }
__device__ __forceinline__ float fsig(float x) { return frcp(1.f + __expf(-x)); }
__device__ __forceinline__ float ftanh(float x) {
  x = fminf(fmaxf(x, -15.f), 15.f);
  float e = __expf(2.f * x);
  return 1.f - 2.f * frcp(e + 1.f);
}

// ---- XCD-local primitives ----
__device__ __forceinline__ int read_xcc_id() {
  int x;
  asm volatile("s_getreg_b32 %0, hwreg(HW_REG_XCC_ID)" : "=s"(x));
  return x & 7;
}
__device__ __forceinline__ void store_x4_sc0(f16* p, f16x8 v) {
  asm volatile("global_store_dwordx4 %0, %1, off sc0" :: "v"(p), "v"(v) : "memory");
}
__device__ __forceinline__ f16x8 load_x4_sc0(const f16* p) {   // no waitcnt!
  f16x8 r;
  asm volatile("global_load_dwordx4 %0, %1, off sc0" : "=v"(r) : "v"(p) : "memory");
  return r;
}
__device__ __forceinline__ void waitcnt_vm0() {
  asm volatile("s_waitcnt vmcnt(0)" ::: "memory");
}
__device__ __forceinline__ void atomic_inc_l2(int* p) {
  int one = 1;
  asm volatile("global_atomic_add %0, %1, off" :: "v"(p), "v"(one) : "memory");
}
__device__ __forceinline__ int load_i32_sc0(const int* p) {
  int r;
  asm volatile("global_load_dword %0, %1, off sc0\n\ts_waitcnt vmcnt(0)"
               : "=v"(r) : "v"(p) : "memory");
  return r;
}
// MALL-coherent poll (bypasses possibly-stale L2 copy; cannot livelock)
__device__ __forceinline__ int load_i32_sc0sc1(const int* p) {
  int r;
  asm volatile("global_load_dword %0, %1, off sc0 sc1\n\ts_waitcnt vmcnt(0)"
               : "=v"(r) : "v"(p) : "memory");
  return r;
}

// ---------------------------------------------------------------------------
// prep: lengths[b], zero slot/barrier counters, zero h-buffer[0]
// ---------------------------------------------------------------------------
__global__ void prep_kernel(const int* __restrict__ seq, int* __restrict__ lengths,
                            int* __restrict__ slotc, int* __restrict__ cnt,
                            f16* __restrict__ hbuf) {
  const int b = blockIdx.x, tid = threadIdx.x;
  __shared__ int red[256];
  int c = 0;
  for (int t = tid; t < Tn; t += 256) c += (seq[b * Tn + t] != 0) ? 1 : 0;
  red[tid] = c;
  __syncthreads();
  for (int s = 128; s > 0; s >>= 1) { if (tid < s) red[tid] += red[tid + s]; __syncthreads(); }
  if (tid == 0) lengths[b] = red[0];
  if (b == 0 && tid < 8) { slotc[tid * CSTRIDE] = 0; cnt[tid * CSTRIDE] = 0; }
  f16* row = hbuf + (size_t)b * Hn;   // hbuf[0][b][:]
  for (int k = tid; k < Hn; k += 256) row[k] = (f16)0.f;
}

// ---------------------------------------------------------------------------
// Persistent cooperative LSTM. 256 blocks x 145KB LDS => 1 block/CU => exactly
// 32 blocks per XCD. group = physical XCD (HW_REG_XCC_ID), slot = XCD-local
// ticket. Block: batches xcd*32..+32, h-cols slot*16..+16.
// R15 = R12's twice-proven skeleton, byte-identical EXCEPT the poll gains a
// two-phase fallback: sc0 fast path (L2 hit) -> after 256 failures, sc0 sc1
// (MALL-coherent) loads. Empirical law from R7/R13/R14 collapses: a poll that
// starts before the block-wide x-stage VMEM phase livelocks on a stale L2
// copy of the counter line (no-flag atomics appear to execute past L2);
// sc1 reads always see fresh values (R5 evidence), so the fallback converts
// any residual livelock into a ~40us rescue.
// Sync skeleton (DO NOT ALTER): (A) hstage; wave-0 store; all-thread vmcnt0;
// (B); tid0 inc; all-wave x-stage; wave-0 poll; (C); h load; (D).
// ---------------------------------------------------------------------------
__global__ __launch_bounds__(256, 1)
void lstm_kernel(const int* __restrict__ seq, const float* __restrict__ emb,
                 const float* __restrict__ Wi, const float* __restrict__ Wh,
                 const float* __restrict__ bl,
                 const int* __restrict__ lengths, int* __restrict__ slotc,
                 int* __restrict__ cnt, f16* __restrict__ hbuf)
{
  __shared__ f16 act[GB * LDK];                // [x_t ; h_t] for 32 batches, swizzled
  __shared__ f16 wt[64 * LDK];                 // staging only (dead after init)
  __shared__ __align__(16) f16 hstage[GB][NH];
  __shared__ int s_ids[2];

  const int tid  = threadIdx.x;
  const int lane = tid & 63;
  const int wv   = tid >> 6;

  if (tid == 0) {
    int x = read_xcc_id();
    s_ids[0] = x;
    s_ids[1] = __hip_atomic_fetch_add(&slotc[x * CSTRIDE], 1,
                                      __ATOMIC_RELAXED, __HIP_MEMORY_SCOPE_AGENT) & 31;
  }
  __syncthreads();
  const int xcd   = s_ids[0];
  const int slot  = s_ids[1];
  const int bbase = xcd * GB;
  int* const bar  = cnt + xcd * CSTRIDE;

  // ---- stage weights into LDS (once): wt[c][k], c = w*16 + gate*4 + hloc ----
  {
    const int c = tid & 63, k0 = tid >> 6;
    const int gate = (c >> 2) & 3, w = c >> 4, hl = c & 3;
    const int gc = gate * Hn + slot * NH + w * 4 + hl;
    for (int k = k0; k < KKn; k += 4) {
      float wval = (k < En) ? Wi[(size_t)k * G4n + gc] : Wh[(size_t)(k - En) * G4n + gc];
      wt[A_IDX(c, k)] = (f16)wval;
    }
  }

  const int ca   = lane & 15;          // col within wave's n-tile
  const int gate = ca >> 2, hloc = ca & 3;
  const float bias = bl[gate * Hn + slot * NH + wv * 4 + hloc];
  const int r0 = (lane >> 4) * 4;      // C/D row base (j=0)
  const bool owner = (ca & 12) == 0;   // gate-0 lanes own (row, hcol) state
  const bool isg = (gate == 2);
  const int koff = (lane >> 4) * 8;

  int   lens[2][4];
  float hreg[2][4] = {{0,0,0,0},{0,0,0,0}};
  float creg[2][4] = {{0,0,0,0},{0,0,0,0}};
#pragma unroll
  for (int mt = 0; mt < 2; ++mt)
#pragma unroll
    for (int j = 0; j < 4; ++j)
      lens[mt][j] = lengths[bbase + mt * 16 + r0 + j];

  // ---- initial staging: x(0) and h(0)=0 (plain loads; dispatch-boundary coherent)
#pragma unroll
  for (int pass = 0; pass < 4; ++pass) {
    const int r = wv * 2 + (lane >> 5) + pass * 8;
    int tok = seq[(size_t)(bbase + r) * Tn + 0];
    const float4* er = (const float4*)(emb + (size_t)tok * En + (lane & 31) * 8);
    float4 v0 = er[0], v1 = er[1];
    f16x8 o = { (f16)v0.x,(f16)v0.y,(f16)v0.z,(f16)v0.w,
                (f16)v1.x,(f16)v1.y,(f16)v1.z,(f16)v1.w };
    *(f16x8*)&act[A_IDX(r, (lane & 31) * 8)] = o;
  }
  for (int r = wv; r < GB; r += 4) {
    f16x8 hv = *(const f16x8*)(hbuf + (size_t)(bbase + r) * Hn + lane * 8);
    *(f16x8*)&act[A_IDX(r, En + lane * 8)] = hv;
  }
  __syncthreads();

  // ---- time-invariant B fragments -> registers, pinned via opaque asm ----
  f16x8 bfrag[24];
#pragma unroll
  for (int ki = 0; ki < 24; ++ki) {
    bfrag[ki] = *(const f16x8*)&wt[A_IDX(wv * 16 + ca, ki * 32 + koff)];
    asm volatile("" : "+v"(bfrag[ki]));
  }

  int cur = 0;

  for (int t = 0; t < Tn; ++t) {
    f32x4 acc[2] = {{0,0,0,0},{0,0,0,0}};
#pragma unroll
    for (int ki = 0; ki < 24; ++ki) {
      const int kt = ki * 32;
      f16x8 a0 = *(const f16x8*)&act[A_IDX(ca, kt + koff)];
      f16x8 a1 = *(const f16x8*)&act[A_IDX(16 + ca, kt + koff)];
      acc[0] = __builtin_amdgcn_mfma_f32_16x16x32_f16(a0, bfrag[ki], acc[0], 0, 0, 0);
      acc[1] = __builtin_amdgcn_mfma_f32_16x16x32_f16(a1, bfrag[ki], acc[1], 0, 0, 0);
    }

    // pre-activate on ALL lanes (one exp path: tanh(v) = 2*sig(2v)-1)
    float av[2][4];
#pragma unroll
    for (int mt = 0; mt < 2; ++mt)
#pragma unroll
      for (int j = 0; j < 4; ++j) {
        float v = acc[mt][j] + bias;
        float s = fsig(isg ? 2.f * v : v);
        av[mt][j] = isg ? (2.f * s - 1.f) : s;
      }

    // gather activated f/g/o onto gate-0 lanes; owners update c/h
#pragma unroll
    for (int mt = 0; mt < 2; ++mt) {
      float fv[4], gv[4], ov[4];
#pragma unroll
      for (int j = 0; j < 4; ++j) {
        fv[j] = __shfl_xor(av[mt][j], 4, 64);
        gv[j] = __shfl_xor(av[mt][j], 8, 64);
        ov[j] = __shfl_xor(av[mt][j], 12, 64);
      }
      if (owner) {
#pragma unroll
        for (int j = 0; j < 4; ++j) {
          float cn = fv[j] * creg[mt][j] + av[mt][j] * gv[j];
          float hn = ov[j] * (2.f * fsig(2.f * cn) - 1.f);
          if (t < lens[mt][j]) { creg[mt][j] = cn; hreg[mt][j] = hn; }
          hstage[mt * 16 + r0 + j][wv * 4 + hloc] = (f16)hreg[mt][j];
        }
      }
    }
    __syncthreads();                                  // (A) hstage complete

    const int nxt = cur ^ 1;
    if (tid < 64) {                                   // wave 0: 32 rows x 32B -> L2
      const int row = tid >> 1, half = tid & 1;
      f16x8 v = ((const f16x8*)&hstage[row][0])[half];
      f16* dst = hbuf + ((size_t)nxt * Bn + (bbase + row)) * Hn + slot * NH + half * 8;
      store_x4_sc0(dst, v);
    }
    waitcnt_vm0();
    __syncthreads();                                  // (B) h tile in L2
    if (t == Tn - 1) break;

    if (tid == 0) atomic_inc_l2(bar);                 // publish step t

    // stage x(t+1) (all waves; this VMEM phase delays the poll -- load-bearing)
#pragma unroll
    for (int pass = 0; pass < 4; ++pass) {
      const int r = wv * 2 + (lane >> 5) + pass * 8;
      int tok = seq[(size_t)(bbase + r) * Tn + (t + 1)];
      const float4* er = (const float4*)(emb + (size_t)tok * En + (lane & 31) * 8);
      float4 v0 = er[0], v1 = er[1];
      f16x8 o = { (f16)v0.x,(f16)v0.y,(f16)v0.z,(f16)v0.w,
                  (f16)v1.x,(f16)v1.y,(f16)v1.z,(f16)v1.w };
      *(f16x8*)&act[A_IDX(r, (lane & 31) * 8)] = o;
    }

    // wave 0 polls: sc0 fast path, sc1 rescue after 256 failures
    if (wv == 0) {
      const int target = NB * (t + 1);
      int guard = 0;
      while (load_i32_sc0(bar) < target) {
        if (++guard > 256) {                          // stale-L2 signature -> MALL reads
          while (load_i32_sc0sc1(bar) < target) {
            if (++guard > (1 << 14)) break;           // degrade, never wedge
            __builtin_amdgcn_s_sleep(2);
          }
          break;
        }
        __builtin_amdgcn_s_sleep(1);
      }
    }
    __syncthreads();                                  // (C)

    // load h(t+1): 8 rows/wave, 16B/lane, sc0 (L1-bypass, L2-hit)
    {
      const f16* hb = hbuf + (size_t)nxt * Bn * Hn;
      f16x8 hv[8];
#pragma unroll
      for (int i = 0; i < 8; ++i)
        hv[i] = load_x4_sc0(hb + (size_t)(bbase + wv + i * 4) * Hn + lane * 8);
      waitcnt_vm0();
#pragma unroll
      for (int i = 0; i < 8; ++i)
        *(f16x8*)&act[A_IDX(wv + i * 4, En + lane * 8)] = hv[i];
    }
    __syncthreads();                                  // (D)
    cur = nxt;
  }
}

// ---------------------------------------------------------------------------
// FF head: hidden = tanh(h @ W1 + b1); logits = hidden @ W2 + b2; softmax.
// Final h lives in hbuf[0] (t=511 writes buffer 0).
// ---------------------------------------------------------------------------
__global__ void ff_kernel(const f16* __restrict__ hbuf0, const float* __restrict__ W1,
                          const float* __restrict__ b1, const float* __restrict__ W2,
                          const float* __restrict__ b2, float* __restrict__ out) {
  const int b = blockIdx.x, tid = threadIdx.x;
  __shared__ float hl[Hn];
  __shared__ float hid[FHn];
  __shared__ float red0[256], red1[256];
  for (int k = tid; k < Hn; k += 256) hl[k] = (float)hbuf0[(size_t)b * Hn + k];
  __syncthreads();
  for (int j = tid; j < FHn; j += 256) {
    float s = b1[j];
    for (int k = 0; k < Hn; ++k) s += hl[k] * W1[(size_t)k * FHn + j];
    hid[j] = ftanh(s);
  }
  __syncthreads();
  float p0 = 0.f, p1 = 0.f;
  for (int j = tid; j < FHn; j += 256) {
    p0 += hid[j] * W2[j * 2 + 0];
    p1 += hid[j] * W2[j * 2 + 1];
  }
  red0[tid] = p0; red1[tid] = p1;
  __syncthreads();
  for (int s = 128; s > 0; s >>= 1) {
    if (tid < s) { red0[tid] += red0[tid + s]; red1[tid] += red1[tid + s]; }
    __syncthreads();
  }
  if (tid == 0) {
    float l0 = red0[0] + b2[0], l1 = red1[0] + b2[1];
    float m = fmaxf(l0, l1);
    float e0 = __expf(l0 - m), e1 = __expf(l1 - m);
    float inv = frcp(e0 + e1);
    out[b * 2 + 0] = e0 * inv;
    out[b * 2 + 1] = e1 * inv;
  }
}

// ---------------------------------------------------------------------------
extern "C" void kernel_launch(void* const* d_in, const int* in_sizes, int n_in,
                              void* d_out, int out_size, void* d_ws, size_t ws_size,
                              hipStream_t stream) {
  const int*   seq = (const int*)d_in[0];
  const float* emb = (const float*)d_in[1];
  const float* Wi  = (const float*)d_in[2];
  const float* Wh  = (const float*)d_in[3];
  const float* bl  = (const float*)d_in[4];
  const float* W1  = (const float*)d_in[5];
  const float* b1  = (const float*)d_in[6];
  const float* W2  = (const float*)d_in[7];
  const float* b2  = (const float*)d_in[8];
  (void)in_sizes; (void)n_in; (void)out_size; (void)ws_size;

  char* ws      = (char*)d_ws;
  int*  lengths = (int*)ws;                 // 1 KB
  int*  slotc   = (int*)(ws + 1024);        // 8 counters, 256B apart
  int*  cnt     = (int*)(ws + 4096);        // 8 counters, 256B apart
  f16*  hbuf    = (f16*)(ws + 8192);        // 2 * 256 * 512 * 2B = 512 KB

  prep_kernel<<<dim3(Bn), dim3(256), 0, stream>>>(seq, lengths, slotc, cnt, hbuf);

  void* args[] = { (void*)&seq, (void*)&emb, (void*)&Wi, (void*)&Wh, (void*)&bl,
                   (void*)&lengths, (void*)&slotc, (void*)&cnt, (void*)&hbuf };
  (void)hipLaunchCooperativeKernel((void*)lstm_kernel, dim3(256), dim3(256), args, 0, stream);

  ff_kernel<<<dim3(Bn), dim3(256), 0, stream>>>(hbuf, W1, b1, W2, b2, (float*)d_out);
}